// Round 10
// baseline (386.264 us; speedup 1.0000x reference)
//
#include <hip/hip_runtime.h>

#define NN 100000
#define NE 1600000
#define TN 16        // encoder tile
#define TNL 32       // sage-layer tile
#define NBK 391      // ceil(NN/256) buckets of 256 nodes
#define BCAP 5120    // per-bucket edge capacity (mean 4096)
#define CTILE 8192   // edges per workgroup in bucket_scatter

static constexpr float BN_EPS = 1e-5f;
static constexpr float NORM_EPS = 1e-12f;

typedef unsigned int u32;
typedef unsigned short u16;
typedef __attribute__((ext_vector_type(8))) short short8;
typedef __attribute__((ext_vector_type(4))) float f32x4;

// ---------------- bf16 helpers ----------------
__device__ __forceinline__ float bflo(u32 u) {
    u32 v = u << 16; float f; __builtin_memcpy(&f, &v, 4); return f;
}
__device__ __forceinline__ float bfhi(u32 u) {
    u32 v = u & 0xffff0000u; float f; __builtin_memcpy(&f, &v, 4); return f;
}
__device__ __forceinline__ u32 packbf(float a, float b) {
    u32 ua, ub; __builtin_memcpy(&ua, &a, 4); __builtin_memcpy(&ub, &b, 4);
    u32 ra = (ua + 0x7fffu + ((ua >> 16) & 1u)) >> 16;
    u32 rb = (ub + 0x7fffu + ((ub >> 16) & 1u)) & 0xffff0000u;
    return ra | rb;
}
__device__ __forceinline__ u16 f2bf(float a) {
    u32 ua; __builtin_memcpy(&ua, &a, 4);
    return (u16)((ua + 0x7fffu + ((ua >> 16) & 1u)) >> 16);
}
__device__ __forceinline__ void acc8(float* s, uint4 v) {
    s[0] += bflo(v.x); s[1] += bfhi(v.x);
    s[2] += bflo(v.y); s[3] += bfhi(v.y);
    s[4] += bflo(v.z); s[5] += bfhi(v.z);
    s[6] += bflo(v.w); s[7] += bfhi(v.w);
}
__device__ __forceinline__ f32x4 mfma16(uint4 a, uint4 b, f32x4 c) {
    return __builtin_amdgcn_mfma_f32_16x16x32_bf16(
        __builtin_bit_cast(short8, a), __builtin_bit_cast(short8, b), c, 0, 0, 0);
}

// ------------- weight fragmentize: W[J][128] f32 -> MFMA B-frag bf16 -------
struct TposeArgs {
    const float* src[10];
    u16* dst[10];
    int rows[10];
};

__global__ void frag_kernel(TposeArgs a) {
    const int m = blockIdx.x;
    const float* __restrict__ s = a.src[m];
    u16* __restrict__ d = a.dst[m];
    const int total = a.rows[m] * 128;
    for (int idx = threadIdx.x; idx < total; idx += 256) {
        const int i = idx & 7;
        const int l = (idx >> 3) & 63;
        const int kk = (idx >> 9) & 3;
        const int jt = idx >> 11;
        const int j = jt * 16 + (l & 15);
        const int k = kk * 32 + ((l >> 4) << 3) + i;
        d[idx] = f2bf(s[j * 128 + k]);
    }
}

// ---------------- CSR build: bucketed, LDS-amortized ----------------
__global__ __launch_bounds__(256, 4)
void bucket_scatter_kernel(const int* __restrict__ e_src, const int* __restrict__ e_dst,
                           int* __restrict__ bcnt, u32* __restrict__ ebuf) {
    __shared__ int h[NBK];
    const int tid = threadIdx.x;
    const int base = blockIdx.x * CTILE;
    const int end = (base + CTILE < NE) ? base + CTILE : NE;
    for (int i = tid; i < NBK; i += 256) h[i] = 0;
    __syncthreads();
    for (int e = base + tid; e < end; e += 256)
        atomicAdd(&h[e_dst[e] >> 8], 1);
    __syncthreads();
    for (int i = tid; i < NBK; i += 256) {
        const int c = h[i];
        h[i] = (c > 0) ? atomicAdd(&bcnt[i], c) : 0;
    }
    __syncthreads();
    for (int e = base + tid; e < end; e += 256) {
        const int d = e_dst[e];
        const int b = d >> 8;
        const int slot = atomicAdd(&h[b], 1);
        if (slot < BCAP)
            ebuf[(size_t)b * BCAP + slot] = (u32)e_src[e] | ((u32)(d & 255) << 17);
    }
}

__global__ void bscan_kernel(const int* __restrict__ bcnt, int* __restrict__ bbase) {
    const int lane = threadIdx.x;   // 64 threads
    const int per = (NBK + 63) / 64;
    int vals[8];
    int s = 0;
    for (int i = 0; i < per; ++i) {
        const int idx = lane * per + i;
        const int v = (idx < NBK) ? bcnt[idx] : 0;
        vals[i] = s; s += v;
    }
    int incl = s;
    for (int off = 1; off < 64; off <<= 1) {
        const int t = __shfl_up(incl, off);
        if (lane >= off) incl += t;
    }
    const int excl = incl - s;
    for (int i = 0; i < per; ++i) {
        const int idx = lane * per + i;
        if (idx < NBK) bbase[idx] = excl + vals[i];
    }
    if (lane == 63) bbase[NBK] = excl + s;
}

__global__ __launch_bounds__(256, 4)
void csr_finalize_kernel(const u32* __restrict__ ebuf, const int* __restrict__ bcnt,
                         const int* __restrict__ bbase,
                         int* __restrict__ row_ptr, float* __restrict__ inv_deg,
                         int* __restrict__ csr_src) {
    __shared__ int cnt[256];
    __shared__ int rc[256];
    const int b = blockIdx.x;
    const int tid = threadIdx.x;
    const int n0 = b << 8;
    const int nb_nodes = (NN - n0 < 256) ? NN - n0 : 256;
    int ecnt = bcnt[b];
    if (ecnt > BCAP) ecnt = BCAP;
    const int gbase = bbase[b];
    const u32* eb = ebuf + (size_t)b * BCAP;
    cnt[tid] = 0;
    __syncthreads();
    for (int e = tid; e < ecnt; e += 256)
        atomicAdd(&cnt[eb[e] >> 17], 1);
    __syncthreads();
    const int myc = cnt[tid];
    int val = myc;
    for (int off = 1; off < 256; off <<= 1) {
        const int t = (tid >= off) ? cnt[tid - off] : 0;
        __syncthreads();
        val += t;
        cnt[tid] = val;
        __syncthreads();
    }
    const int excl = val - myc;
    if (tid < nb_nodes) {
        row_ptr[n0 + tid] = gbase + excl;
        inv_deg[n0 + tid] = 1.0f / (float)(myc < 1 ? 1 : myc);
    }
    rc[tid] = gbase + excl;
    __syncthreads();
    for (int e = tid; e < ecnt; e += 256) {
        const u32 p = eb[e];
        const int pos = atomicAdd(&rc[p >> 17], 1);
        csr_src[pos] = (int)(p & 0x1FFFFu);
    }
    if (b == NBK - 1 && tid == 0) row_ptr[NN] = NE;
}

// ------- encoder: h = relu(x @ W^T + b) via MFMA, writes cm-slice layout ---
// h_cm[cg][node][16] bf16, cg in [0,8): columns [cg*16, cg*16+16)
__global__ __launch_bounds__(256, 6)
void encoder_kernel(const float* __restrict__ x, u16* __restrict__ h_cm,
                    const u16* __restrict__ wfrag, const float* __restrict__ bias) {
    __shared__ uint4 sRows[256];
    const int tid = threadIdx.x;
    const int nb = blockIdx.x * TN;

    {
        const int row = tid >> 4, t = tid & 15;
        const float4* xr = (const float4*)(x + (size_t)(nb + row) * 128 + t * 8);
        const float4 xa = xr[0], xb = xr[1];
        uint4 p;
        p.x = packbf(xa.x, xa.y); p.y = packbf(xa.z, xa.w);
        p.z = packbf(xb.x, xb.y); p.w = packbf(xb.z, xb.w);
        sRows[row * 16 + (t ^ (row & 7))] = p;
    }
    __syncthreads();

    const int lane = tid & 63, wave = tid >> 6;
    const int cl = lane & 15, gq = lane >> 4;
    const int jt0 = wave * 2, jt1 = wave * 2 + 1;
    const uint4* wf = (const uint4*)wfrag;
    f32x4 a0 = {0, 0, 0, 0}, a1 = {0, 0, 0, 0};
    #pragma unroll
    for (int kk = 0; kk < 4; ++kk) {
        const uint4 af = sRows[cl * 16 + ((kk * 4 + gq) ^ (cl & 7))];
        a0 = mfma16(af, wf[(jt0 * 4 + kk) * 64 + lane], a0);
        a1 = mfma16(af, wf[(jt1 * 4 + kk) * 64 + lane], a1);
    }
    const int c0 = jt0 * 16 + cl, c1 = jt1 * 16 + cl;
    const float b0 = bias[c0], b1 = bias[c1];
    __syncthreads();   // MFMA reads done; reuse sRows as store stage
    u16* st = (u16*)sRows;   // [16][128] u16, chunk-swizzled
    #pragma unroll
    for (int r = 0; r < 4; ++r) {
        const int rw = gq * 4 + r;
        st[rw * 128 + (((c0 >> 3) ^ (rw & 7)) << 3) + (c0 & 7)] = f2bf(fmaxf(a0[r] + b0, 0.f));
        st[rw * 128 + (((c1 >> 3) ^ (rw & 7)) << 3) + (c1 & 7)] = f2bf(fmaxf(a1[r] + b1, 0.f));
    }
    __syncthreads();
    // write 8 cm slices: 256 uint4 total
    {
        const int cg = tid >> 5, r = (tid >> 1) & 15, hf = tid & 1;
        const int chunk = cg * 2 + hf;
        ((uint4*)h_cm)[((size_t)cg * NN + nb + r) * 2 + hf] =
            sRows[r * 16 + (chunk ^ (r & 7))];
    }
}

// ------- gather kernel: per (cg, 32-node tile) partial mean over 16 cols ---
// cg = blockIdx&7 -> with round-robin block->XCD dispatch, each XCD's
// working set is one 3.2 MB slice (L2-resident).
__global__ __launch_bounds__(256, 8)
void gather_cm_kernel(const u16* __restrict__ h_cm, u16* __restrict__ mean_cm,
                      const int* __restrict__ row_ptr, const int* __restrict__ csr_src,
                      const float* __restrict__ inv_deg) {
    const int cg = blockIdx.x & 7;
    const int nb = (blockIdx.x >> 3) * 32;
    const int t = threadIdx.x;
    const int g = t >> 3;          // node 0..31
    const int sub = t & 7;
    const int es = sub >> 1;       // edge slot 0..3
    const int hf = sub & 1;        // 16B half of the 32B slice
    const int n = nb + g;
    const uint4* hb = (const uint4*)h_cm + (size_t)cg * NN * 2;
    float acc[8] = {0, 0, 0, 0, 0, 0, 0, 0};
    const int rp0 = row_ptr[n], rp1 = row_ptr[n + 1];
    int e = rp0 + es;
    for (; e + 4 < rp1; e += 8) {   // 2 independent loads in flight
        const int s0 = csr_src[e];
        const int s1 = csr_src[e + 4];
        const uint4 v0 = hb[(size_t)s0 * 2 + hf];
        const uint4 v1 = hb[(size_t)s1 * 2 + hf];
        acc8(acc, v0); acc8(acc, v1);
    }
    if (e < rp1) acc8(acc, hb[(size_t)csr_src[e] * 2 + hf]);
    // reduce across the 4 edge slots (lane bits 1,2)
    #pragma unroll
    for (int i = 0; i < 8; ++i) {
        acc[i] += __shfl_xor(acc[i], 2);
        acc[i] += __shfl_xor(acc[i], 4);
    }
    if (es == 0) {
        const float id = inv_deg[n];
        uint4 mp;
        mp.x = packbf(acc[0] * id, acc[1] * id);
        mp.y = packbf(acc[2] * id, acc[3] * id);
        mp.z = packbf(acc[4] * id, acc[5] * id);
        mp.w = packbf(acc[6] * id, acc[7] * id);
        ((uint4*)mean_cm)[((size_t)cg * NN + n) * 2 + hf] = mp;
    }
}

// ---------------- SAGE matmul layer (MFMA) + optional fused heads ---------
template<int LAST>
__global__ __launch_bounds__(256, 8)
void sage_mm_kernel(const u16* __restrict__ h_cm, const u16* __restrict__ mean_cm,
                    u16* __restrict__ hout_cm, float* __restrict__ o_h,
                    const u16* __restrict__ wlfrag, const float* __restrict__ bl,
                    const u16* __restrict__ wrfrag,
                    const float* __restrict__ bn_g, const float* __restrict__ bn_b,
                    const float* __restrict__ bn_m, const float* __restrict__ bn_v,
                    const u16* __restrict__ o1frag, const float* __restrict__ ob1,
                    const float* __restrict__ ow2, const float* __restrict__ ob2,
                    const u16* __restrict__ c1frag, const float* __restrict__ cb1,
                    const float* __restrict__ cw2, const float* __restrict__ cb2,
                    const u16* __restrict__ b1frag, const float* __restrict__ bb1,
                    const float* __restrict__ bw2, const float* __restrict__ bb2,
                    float* __restrict__ o_order, float* __restrict__ o_cost,
                    float* __restrict__ o_bw) {
    __shared__ uint4 sRows[512];   // 32 rows x 16 chunks, swizzled (8 KB)
    __shared__ uint4 sMean[512];   // 8 KB
    __shared__ float ssb[4][32];
    const int tid = threadIdx.x;
    const int nb = blockIdx.x * TNL;

    // stage h rows + means from cm layout (coalesced per-cg runs)
    {
        const uint4* hs = (const uint4*)h_cm;
        const uint4* ms = (const uint4*)mean_cm;
        #pragma unroll
        for (int p = 0; p < 2; ++p) {
            const int i = tid + p * 256;
            const int cg = i >> 6, r = (i >> 1) & 31, hf = i & 1;
            const int chunk = cg * 2 + hf;
            const size_t gidx = ((size_t)cg * NN + nb + r) * 2 + hf;
            const int lidx = r * 16 + (chunk ^ (r & 7));
            sRows[lidx] = hs[gidx];
            sMean[lidx] = ms[gidx];
        }
    }
    __syncthreads();

    const int lane = tid & 63, wave = tid >> 6;
    const int cl = lane & 15, gq = lane >> 4;
    const int jt0 = wave * 2, jt1 = wave * 2 + 1;
    f32x4 a00 = {0,0,0,0}, a01 = {0,0,0,0}, a10 = {0,0,0,0}, a11 = {0,0,0,0};
    {
        const uint4* wf = (const uint4*)wlfrag;
        #pragma unroll
        for (int kk = 0; kk < 4; ++kk) {
            const int ch = (kk * 4 + gq) ^ (cl & 7);
            const uint4 af0 = sMean[cl * 16 + ch];
            const uint4 af1 = sMean[(16 + cl) * 16 + ch];
            const uint4 b0 = wf[(jt0 * 4 + kk) * 64 + lane];
            const uint4 b1 = wf[(jt1 * 4 + kk) * 64 + lane];
            a00 = mfma16(af0, b0, a00); a01 = mfma16(af0, b1, a01);
            a10 = mfma16(af1, b0, a10); a11 = mfma16(af1, b1, a11);
        }
    }
    {
        const uint4* wf = (const uint4*)wrfrag;
        #pragma unroll
        for (int kk = 0; kk < 4; ++kk) {
            const int ch = (kk * 4 + gq) ^ (cl & 7);
            const uint4 af0 = sRows[cl * 16 + ch];
            const uint4 af1 = sRows[(16 + cl) * 16 + ch];
            const uint4 b0 = wf[(jt0 * 4 + kk) * 64 + lane];
            const uint4 b1 = wf[(jt1 * 4 + kk) * 64 + lane];
            a00 = mfma16(af0, b0, a00); a01 = mfma16(af0, b1, a01);
            a10 = mfma16(af1, b0, a10); a11 = mfma16(af1, b1, a11);
        }
    }

    // epilogue: +bias, row L2-norm (cross-wave), BN(eval), relu
    const int c0 = jt0 * 16 + cl, c1 = jt1 * 16 + cl;
    const float bl0 = bl[c0], bl1 = bl[c1];
    float t00[4], t01[4], t10[4], t11[4], ss0[4], ss1[4];
    #pragma unroll
    for (int r = 0; r < 4; ++r) {
        t00[r] = a00[r] + bl0; t01[r] = a01[r] + bl1;
        t10[r] = a10[r] + bl0; t11[r] = a11[r] + bl1;
        ss0[r] = t00[r] * t00[r] + t01[r] * t01[r];
        ss1[r] = t10[r] * t10[r] + t11[r] * t11[r];
    }
    #pragma unroll
    for (int m = 1; m <= 8; m <<= 1) {
        #pragma unroll
        for (int r = 0; r < 4; ++r) {
            ss0[r] += __shfl_xor(ss0[r], m);
            ss1[r] += __shfl_xor(ss1[r], m);
        }
    }
    if (cl == 0) {
        #pragma unroll
        for (int r = 0; r < 4; ++r) {
            ssb[wave][gq * 4 + r] = ss0[r];
            ssb[wave][16 + gq * 4 + r] = ss1[r];
        }
    }
    __syncthreads();   // also: all MFMA reads of sMean/sRows done

    const float sc0 = bn_g[c0] * rsqrtf(bn_v[c0] + BN_EPS);
    const float sc1 = bn_g[c1] * rsqrtf(bn_v[c1] + BN_EPS);
    const float m0 = bn_m[c0], m1 = bn_m[c1];
    const float bb0 = bn_b[c0], bb1v = bn_b[c1];
    float f00[4], f01[4], f10[4], f11[4];
    #pragma unroll
    for (int r = 0; r < 4; ++r) {
        const int rw0 = gq * 4 + r, rw1 = 16 + rw0;
        const float tot0 = ssb[0][rw0] + ssb[1][rw0] + ssb[2][rw0] + ssb[3][rw0];
        const float tot1 = ssb[0][rw1] + ssb[1][rw1] + ssb[2][rw1] + ssb[3][rw1];
        const float inv0 = 1.0f / fmaxf(sqrtf(tot0), NORM_EPS);
        const float inv1 = 1.0f / fmaxf(sqrtf(tot1), NORM_EPS);
        f00[r] = fmaxf((t00[r] * inv0 - m0) * sc0 + bb0, 0.f);
        f01[r] = fmaxf((t01[r] * inv0 - m1) * sc1 + bb1v, 0.f);
        f10[r] = fmaxf((t10[r] * inv1 - m0) * sc0 + bb0, 0.f);
        f11[r] = fmaxf((t11[r] * inv1 - m1) * sc1 + bb1v, 0.f);
    }

    if (!LAST) {
        // stage output (sMean dead) then write 8 cm slices coalesced
        u16* st = (u16*)sMean;   // [32][128] u16, chunk-swizzled
        #pragma unroll
        for (int r = 0; r < 4; ++r) {
            const int rw0 = gq * 4 + r, rw1 = 16 + rw0;
            st[rw0 * 128 + (((c0 >> 3) ^ (rw0 & 7)) << 3) + (c0 & 7)] = f2bf(f00[r]);
            st[rw0 * 128 + (((c1 >> 3) ^ (rw0 & 7)) << 3) + (c1 & 7)] = f2bf(f01[r]);
            st[rw1 * 128 + (((c0 >> 3) ^ (rw1 & 7)) << 3) + (c0 & 7)] = f2bf(f10[r]);
            st[rw1 * 128 + (((c1 >> 3) ^ (rw1 & 7)) << 3) + (c1 & 7)] = f2bf(f11[r]);
        }
        __syncthreads();
        uint4* dst = (uint4*)hout_cm;
        #pragma unroll
        for (int p = 0; p < 2; ++p) {
            const int i = tid + p * 256;
            const int cg = i >> 6, r = (i >> 1) & 31, hf = i & 1;
            const int chunk = cg * 2 + hf;
            dst[((size_t)cg * NN + nb + r) * 2 + hf] = sMean[r * 16 + (chunk ^ (r & 7))];
        }
        return;
    }

    // LAST: o_h f32 (row-major output) via two staged passes
    {
        float* stf = (float*)sMean;
        #pragma unroll
        for (int r = 0; r < 4; ++r) {
            const int rw0 = gq * 4 + r;
            stf[rw0 * 128 + c0] = f00[r];
            stf[rw0 * 128 + c1] = f01[r];
        }
        __syncthreads();
        float4* dst0 = (float4*)(o_h + (size_t)nb * 128);
        dst0[tid] = ((const float4*)stf)[tid];
        dst0[tid + 256] = ((const float4*)stf)[tid + 256];
        __syncthreads();
        #pragma unroll
        for (int r = 0; r < 4; ++r) {
            const int rw0 = gq * 4 + r;
            stf[rw0 * 128 + c0] = f10[r];
            stf[rw0 * 128 + c1] = f11[r];
        }
        __syncthreads();
        float4* dst1 = (float4*)(o_h + (size_t)(nb + 16) * 128);
        dst1[tid] = ((const float4*)stf)[tid];
        dst1[tid + 256] = ((const float4*)stf)[tid + 256];
    }

    // restage bf16 h into sRows for fused heads
    u16* sr16 = (u16*)sRows;
    #pragma unroll
    for (int r = 0; r < 4; ++r) {
        const int rw0 = gq * 4 + r, rw1 = 16 + rw0;
        sr16[rw0 * 128 + (((c0 >> 3) ^ (rw0 & 7)) << 3) + (c0 & 7)] = f2bf(f00[r]);
        sr16[rw0 * 128 + (((c1 >> 3) ^ (rw0 & 7)) << 3) + (c1 & 7)] = f2bf(f01[r]);
        sr16[rw1 * 128 + (((c0 >> 3) ^ (rw1 & 7)) << 3) + (c0 & 7)] = f2bf(f10[r]);
        sr16[rw1 * 128 + (((c1 >> 3) ^ (rw1 & 7)) << 3) + (c1 & 7)] = f2bf(f11[r]);
    }
    __syncthreads();

    // ---- order head: hidden 128, then dot with ow2 ----
    {
        const uint4* wf = (const uint4*)o1frag;
        f32x4 h00 = {0,0,0,0}, h01 = {0,0,0,0}, h10 = {0,0,0,0}, h11 = {0,0,0,0};
        #pragma unroll
        for (int kk = 0; kk < 4; ++kk) {
            const int ch = (kk * 4 + gq) ^ (cl & 7);
            const uint4 af0 = sRows[cl * 16 + ch];
            const uint4 af1 = sRows[(16 + cl) * 16 + ch];
            const uint4 b0 = wf[(jt0 * 4 + kk) * 64 + lane];
            const uint4 b1 = wf[(jt1 * 4 + kk) * 64 + lane];
            h00 = mfma16(af0, b0, h00); h01 = mfma16(af0, b1, h01);
            h10 = mfma16(af1, b0, h10); h11 = mfma16(af1, b1, h11);
        }
        const float hb0 = ob1[c0], hb1 = ob1[c1];
        const float w20 = ow2[c0], w21 = ow2[c1];
        float p0[4], p1[4];
        #pragma unroll
        for (int r = 0; r < 4; ++r) {
            p0[r] = fmaxf(h00[r] + hb0, 0.f) * w20 + fmaxf(h01[r] + hb1, 0.f) * w21;
            p1[r] = fmaxf(h10[r] + hb0, 0.f) * w20 + fmaxf(h11[r] + hb1, 0.f) * w21;
        }
        #pragma unroll
        for (int m = 1; m <= 8; m <<= 1) {
            #pragma unroll
            for (int r = 0; r < 4; ++r) {
                p0[r] += __shfl_xor(p0[r], m);
                p1[r] += __shfl_xor(p1[r], m);
            }
        }
        if (cl == 0) {
            #pragma unroll
            for (int r = 0; r < 4; ++r) {
                ssb[wave][gq * 4 + r] = p0[r];
                ssb[wave][16 + gq * 4 + r] = p1[r];
            }
        }
        __syncthreads();
        if (tid < 32)
            o_order[nb + tid] = ssb[0][tid] + ssb[1][tid] + ssb[2][tid] + ssb[3][tid] + ob2[0];
        __syncthreads();
    }

    // ---- cost / bullwhip heads: hidden 64 (one 16-col tile per wave) ----
    const u16* hfr[2] = {c1frag, b1frag};
    const float* hb1a[2] = {cb1, bb1};
    const float* hw2a[2] = {cw2, bw2};
    const float* hb2a[2] = {cb2, bb2};
    float* outs[2] = {o_cost, o_bw};
    #pragma unroll
    for (int ph = 0; ph < 2; ++ph) {
        const uint4* wf = (const uint4*)hfr[ph];
        f32x4 g0 = {0,0,0,0}, g1 = {0,0,0,0};
        #pragma unroll
        for (int kk = 0; kk < 4; ++kk) {
            const int ch = (kk * 4 + gq) ^ (cl & 7);
            const uint4 af0 = sRows[cl * 16 + ch];
            const uint4 af1 = sRows[(16 + cl) * 16 + ch];
            const uint4 b = wf[(wave * 4 + kk) * 64 + lane];
            g0 = mfma16(af0, b, g0);
            g1 = mfma16(af1, b, g1);
        }
        const int cc = wave * 16 + cl;
        const float hb = hb1a[ph][cc], w2 = hw2a[ph][cc];
        float p0[4], p1[4];
        #pragma unroll
        for (int r = 0; r < 4; ++r) {
            p0[r] = fmaxf(g0[r] + hb, 0.f) * w2;
            p1[r] = fmaxf(g1[r] + hb, 0.f) * w2;
        }
        #pragma unroll
        for (int m = 1; m <= 8; m <<= 1) {
            #pragma unroll
            for (int r = 0; r < 4; ++r) {
                p0[r] += __shfl_xor(p0[r], m);
                p1[r] += __shfl_xor(p1[r], m);
            }
        }
        if (cl == 0) {
            #pragma unroll
            for (int r = 0; r < 4; ++r) {
                ssb[wave][gq * 4 + r] = p0[r];
                ssb[wave][16 + gq * 4 + r] = p1[r];
            }
        }
        __syncthreads();
        if (tid < 32)
            outs[ph][nb + tid] = ssb[0][tid] + ssb[1][tid] + ssb[2][tid] + ssb[3][tid] + hb2a[ph][0];
        __syncthreads();
    }
}

extern "C" void kernel_launch(void* const* d_in, const int* in_sizes, int n_in,
                              void* d_out, int out_size, void* d_ws, size_t ws_size,
                              hipStream_t stream) {
    (void)in_sizes; (void)n_in; (void)out_size;

    const float* x       = (const float*)d_in[0];
    const int*   ei      = (const int*)d_in[1];
    const float* enc_w   = (const float*)d_in[2];
    const float* enc_b   = (const float*)d_in[3];
    const float* ll_w    = (const float*)d_in[4];
    const float* ll_b    = (const float*)d_in[5];
    const float* lr_w    = (const float*)d_in[6];
    const float* bn_g    = (const float*)d_in[7];
    const float* bn_b    = (const float*)d_in[8];
    const float* bn_m    = (const float*)d_in[9];
    const float* bn_v    = (const float*)d_in[10];
    const float* out_w1  = (const float*)d_in[11];
    const float* out_b1  = (const float*)d_in[12];
    const float* out_w2  = (const float*)d_in[13];
    const float* out_b2  = (const float*)d_in[14];
    const float* cost_w1 = (const float*)d_in[15];
    const float* cost_b1 = (const float*)d_in[16];
    const float* cost_w2 = (const float*)d_in[17];
    const float* cost_b2 = (const float*)d_in[18];
    const float* bw_w1   = (const float*)d_in[19];
    const float* bw_b1   = (const float*)d_in[20];
    const float* bw_w2   = (const float*)d_in[21];
    const float* bw_b2   = (const float*)d_in[22];

    const int* e_src = ei;
    const int* e_dst = ei + NE;

    float* o_order = (float*)d_out;
    float* o_cost  = o_order + NN;
    float* o_bw    = o_cost + NN;
    float* o_h     = o_bw + NN;   // NN*128 f32 (final h)

    // workspace layout
    u16* hA      = (u16*)d_ws;                  // NN*128 bf16 (cm slices)
    u16* hB      = hA + (size_t)NN * 128;       // NN*128 bf16 (cm slices)
    u16* mean_cm = hB + (size_t)NN * 128;       // NN*128 bf16 (cm slices)
    u16* wt      = mean_cm + (size_t)NN * 128;  // 147456 bf16 (fragment layout)
    u16* wt_enc  = wt;
    u16* wt_ll   = wt + 16384;
    u16* wt_lr   = wt + 16384 * 4;
    u16* wt_out1 = wt + 16384 * 7;
    u16* wt_c1   = wt + 16384 * 8;
    u16* wt_bw1  = wt + 16384 * 8 + 8192;
    int* row_ptr  = (int*)(wt + 147456);        // NN+1 (+pad)
    float* inv_deg = (float*)(row_ptr + NN + 4);
    int* csr_src  = (int*)(inv_deg + NN);       // NE
    int* bcnt     = csr_src + NE;               // NBK+1
    int* bbase    = bcnt + NBK + 1;             // NBK+1
    u32* ebuf     = (u32*)(bbase + NBK + 1);    // NBK*BCAP

    const size_t need = (size_t)((char*)(ebuf + (size_t)NBK * BCAP) - (char*)d_ws);
    if (ws_size < need) return;

    (void)hipMemsetAsync(bcnt, 0, (NBK + 1) * sizeof(int), stream);

    TposeArgs ta;
    ta.src[0] = enc_w;          ta.dst[0] = wt_enc;          ta.rows[0] = 128;
    ta.src[1] = ll_w;           ta.dst[1] = wt_ll;           ta.rows[1] = 128;
    ta.src[2] = ll_w + 16384;   ta.dst[2] = wt_ll + 16384;   ta.rows[2] = 128;
    ta.src[3] = ll_w + 32768;   ta.dst[3] = wt_ll + 32768;   ta.rows[3] = 128;
    ta.src[4] = lr_w;           ta.dst[4] = wt_lr;           ta.rows[4] = 128;
    ta.src[5] = lr_w + 16384;   ta.dst[5] = wt_lr + 16384;   ta.rows[5] = 128;
    ta.src[6] = lr_w + 32768;   ta.dst[6] = wt_lr + 32768;   ta.rows[6] = 128;
    ta.src[7] = out_w1;         ta.dst[7] = wt_out1;         ta.rows[7] = 128;
    ta.src[8] = cost_w1;        ta.dst[8] = wt_c1;           ta.rows[8] = 64;
    ta.src[9] = bw_w1;          ta.dst[9] = wt_bw1;          ta.rows[9] = 64;
    frag_kernel<<<10, 256, 0, stream>>>(ta);

    bucket_scatter_kernel<<<(NE + CTILE - 1) / CTILE, 256, 0, stream>>>(e_src, e_dst, bcnt, ebuf);
    bscan_kernel<<<1, 64, 0, stream>>>(bcnt, bbase);
    csr_finalize_kernel<<<NBK, 256, 0, stream>>>(ebuf, bcnt, bbase, row_ptr, inv_deg, csr_src);

    const int NG = (NN / TNL) * 8;   // gather grid: 3125 tiles x 8 col-groups
    encoder_kernel<<<NN / TN, 256, 0, stream>>>(x, hA, wt_enc, enc_b);

    gather_cm_kernel<<<NG, 256, 0, stream>>>(hA, mean_cm, row_ptr, csr_src, inv_deg);
    sage_mm_kernel<0><<<NN / TNL, 256, 0, stream>>>(hA, mean_cm, hB, nullptr,
        wt_ll, ll_b, wt_lr, bn_g, bn_b, bn_m, bn_v,
        nullptr, nullptr, nullptr, nullptr, nullptr, nullptr, nullptr, nullptr,
        nullptr, nullptr, nullptr, nullptr, nullptr, nullptr, nullptr);

    gather_cm_kernel<<<NG, 256, 0, stream>>>(hB, mean_cm, row_ptr, csr_src, inv_deg);
    sage_mm_kernel<0><<<NN / TNL, 256, 0, stream>>>(hB, mean_cm, hA, nullptr,
        wt_ll + 16384, ll_b + 128, wt_lr + 16384,
        bn_g + 128, bn_b + 128, bn_m + 128, bn_v + 128,
        nullptr, nullptr, nullptr, nullptr, nullptr, nullptr, nullptr, nullptr,
        nullptr, nullptr, nullptr, nullptr, nullptr, nullptr, nullptr);

    gather_cm_kernel<<<NG, 256, 0, stream>>>(hA, mean_cm, row_ptr, csr_src, inv_deg);
    sage_mm_kernel<1><<<NN / TNL, 256, 0, stream>>>(hA, mean_cm, nullptr, o_h,
        wt_ll + 32768, ll_b + 256, wt_lr + 32768,
        bn_g + 256, bn_b + 256, bn_m + 256, bn_v + 256,
        wt_out1, out_b1, out_w2, out_b2,
        wt_c1, cost_b1, cost_w2, cost_b2,
        wt_bw1, bw_b1, bw_w2, bw_b2,
        o_order, o_cost, o_bw);
}

// Round 11
// 373.806 us; speedup vs baseline: 1.0333x; 1.0333x over previous
//
#include <hip/hip_runtime.h>

#define NN 100000
#define NE 1600000
#define TN 16        // encoder tile
#define TNL 32       // sage-layer tile
#define NBK 391      // ceil(NN/256) buckets of 256 nodes
#define BCAP 5120    // per-bucket edge capacity (mean 4096)
#define CTILE 8192   // edges per workgroup in bucket_scatter

static constexpr float BN_EPS = 1e-5f;
static constexpr float NORM_EPS = 1e-12f;

typedef unsigned int u32;
typedef unsigned short u16;
typedef __attribute__((ext_vector_type(8))) short short8;
typedef __attribute__((ext_vector_type(4))) float f32x4;

// ---------------- bf16 helpers ----------------
__device__ __forceinline__ float bflo(u32 u) {
    u32 v = u << 16; float f; __builtin_memcpy(&f, &v, 4); return f;
}
__device__ __forceinline__ float bfhi(u32 u) {
    u32 v = u & 0xffff0000u; float f; __builtin_memcpy(&f, &v, 4); return f;
}
__device__ __forceinline__ u32 packbf(float a, float b) {
    u32 ua, ub; __builtin_memcpy(&ua, &a, 4); __builtin_memcpy(&ub, &b, 4);
    u32 ra = (ua + 0x7fffu + ((ua >> 16) & 1u)) >> 16;
    u32 rb = (ub + 0x7fffu + ((ub >> 16) & 1u)) & 0xffff0000u;
    return ra | rb;
}
__device__ __forceinline__ u16 f2bf(float a) {
    u32 ua; __builtin_memcpy(&ua, &a, 4);
    return (u16)((ua + 0x7fffu + ((ua >> 16) & 1u)) >> 16);
}
__device__ __forceinline__ void acc8(float* s, uint4 v) {
    s[0] += bflo(v.x); s[1] += bfhi(v.x);
    s[2] += bflo(v.y); s[3] += bfhi(v.y);
    s[4] += bflo(v.z); s[5] += bfhi(v.z);
    s[6] += bflo(v.w); s[7] += bfhi(v.w);
}
__device__ __forceinline__ f32x4 mfma16(uint4 a, uint4 b, f32x4 c) {
    return __builtin_amdgcn_mfma_f32_16x16x32_bf16(
        __builtin_bit_cast(short8, a), __builtin_bit_cast(short8, b), c, 0, 0, 0);
}

// ------------- weight fragmentize: W[J][128] f32 -> MFMA B-frag bf16 -------
struct TposeArgs {
    const float* src[10];
    u16* dst[10];
    int rows[10];
};

__global__ void frag_kernel(TposeArgs a) {
    const int m = blockIdx.x;
    const float* __restrict__ s = a.src[m];
    u16* __restrict__ d = a.dst[m];
    const int total = a.rows[m] * 128;
    for (int idx = threadIdx.x; idx < total; idx += 256) {
        const int i = idx & 7;
        const int l = (idx >> 3) & 63;
        const int kk = (idx >> 9) & 3;
        const int jt = idx >> 11;
        const int j = jt * 16 + (l & 15);
        const int k = kk * 32 + ((l >> 4) << 3) + i;
        d[idx] = f2bf(s[j * 128 + k]);
    }
}

// ---------------- CSR build: bucketed, LDS-amortized ----------------
__global__ __launch_bounds__(256, 4)
void bucket_scatter_kernel(const int* __restrict__ e_src, const int* __restrict__ e_dst,
                           int* __restrict__ bcnt, u32* __restrict__ ebuf) {
    __shared__ int h[NBK];
    const int tid = threadIdx.x;
    const int base = blockIdx.x * CTILE;
    const int end = (base + CTILE < NE) ? base + CTILE : NE;
    for (int i = tid; i < NBK; i += 256) h[i] = 0;
    __syncthreads();
    for (int e = base + tid; e < end; e += 256)
        atomicAdd(&h[e_dst[e] >> 8], 1);
    __syncthreads();
    for (int i = tid; i < NBK; i += 256) {
        const int c = h[i];
        h[i] = (c > 0) ? atomicAdd(&bcnt[i], c) : 0;
    }
    __syncthreads();
    for (int e = base + tid; e < end; e += 256) {
        const int d = e_dst[e];
        const int b = d >> 8;
        const int slot = atomicAdd(&h[b], 1);
        if (slot < BCAP)
            ebuf[(size_t)b * BCAP + slot] = (u32)e_src[e] | ((u32)(d & 255) << 17);
    }
}

__global__ void bscan_kernel(const int* __restrict__ bcnt, int* __restrict__ bbase) {
    const int lane = threadIdx.x;   // 64 threads
    const int per = (NBK + 63) / 64;
    int vals[8];
    int s = 0;
    for (int i = 0; i < per; ++i) {
        const int idx = lane * per + i;
        const int v = (idx < NBK) ? bcnt[idx] : 0;
        vals[i] = s; s += v;
    }
    int incl = s;
    for (int off = 1; off < 64; off <<= 1) {
        const int t = __shfl_up(incl, off);
        if (lane >= off) incl += t;
    }
    const int excl = incl - s;
    for (int i = 0; i < per; ++i) {
        const int idx = lane * per + i;
        if (idx < NBK) bbase[idx] = excl + vals[i];
    }
    if (lane == 63) bbase[NBK] = excl + s;
}

__global__ __launch_bounds__(256, 4)
void csr_finalize_kernel(const u32* __restrict__ ebuf, const int* __restrict__ bcnt,
                         const int* __restrict__ bbase,
                         int* __restrict__ row_ptr, float* __restrict__ inv_deg,
                         int* __restrict__ csr_src) {
    __shared__ int cnt[256];
    __shared__ int rc[256];
    const int b = blockIdx.x;
    const int tid = threadIdx.x;
    const int n0 = b << 8;
    const int nb_nodes = (NN - n0 < 256) ? NN - n0 : 256;
    int ecnt = bcnt[b];
    if (ecnt > BCAP) ecnt = BCAP;
    const int gbase = bbase[b];
    const u32* eb = ebuf + (size_t)b * BCAP;
    cnt[tid] = 0;
    __syncthreads();
    for (int e = tid; e < ecnt; e += 256)
        atomicAdd(&cnt[eb[e] >> 17], 1);
    __syncthreads();
    const int myc = cnt[tid];
    int val = myc;
    for (int off = 1; off < 256; off <<= 1) {
        const int t = (tid >= off) ? cnt[tid - off] : 0;
        __syncthreads();
        val += t;
        cnt[tid] = val;
        __syncthreads();
    }
    const int excl = val - myc;
    if (tid < nb_nodes) {
        row_ptr[n0 + tid] = gbase + excl;
        inv_deg[n0 + tid] = 1.0f / (float)(myc < 1 ? 1 : myc);
    }
    rc[tid] = gbase + excl;
    __syncthreads();
    for (int e = tid; e < ecnt; e += 256) {
        const u32 p = eb[e];
        const int pos = atomicAdd(&rc[p >> 17], 1);
        csr_src[pos] = (int)(p & 0x1FFFFu);
    }
    if (b == NBK - 1 && tid == 0) row_ptr[NN] = NE;
}

// ---------------- encoder: h = relu(x @ W^T + b) via MFMA, bf16 out -------
__global__ __launch_bounds__(256, 6)
void encoder_kernel(const float* __restrict__ x, u16* __restrict__ h_out,
                    const u16* __restrict__ wfrag, const float* __restrict__ bias) {
    __shared__ uint4 sRows[256];
    const int tid = threadIdx.x;
    const int nb = blockIdx.x * TN;

    {
        const int row = tid >> 4, t = tid & 15;
        const float4* xr = (const float4*)(x + (size_t)(nb + row) * 128 + t * 8);
        const float4 xa = xr[0], xb = xr[1];
        uint4 p;
        p.x = packbf(xa.x, xa.y); p.y = packbf(xa.z, xa.w);
        p.z = packbf(xb.x, xb.y); p.w = packbf(xb.z, xb.w);
        sRows[row * 16 + (t ^ (row & 7))] = p;
    }
    __syncthreads();

    const int lane = tid & 63, wave = tid >> 6;
    const int cl = lane & 15, gq = lane >> 4;
    const int jt0 = wave * 2, jt1 = wave * 2 + 1;
    const uint4* wf = (const uint4*)wfrag;
    f32x4 a0 = {0, 0, 0, 0}, a1 = {0, 0, 0, 0};
    #pragma unroll
    for (int kk = 0; kk < 4; ++kk) {
        const uint4 af = sRows[cl * 16 + ((kk * 4 + gq) ^ (cl & 7))];
        a0 = mfma16(af, wf[(jt0 * 4 + kk) * 64 + lane], a0);
        a1 = mfma16(af, wf[(jt1 * 4 + kk) * 64 + lane], a1);
    }
    const int c0 = jt0 * 16 + cl, c1 = jt1 * 16 + cl;
    const float b0 = bias[c0], b1 = bias[c1];
    __syncthreads();   // all MFMA reads of sRows done; reuse as store stage
    u16* st = (u16*)sRows;   // 16 rows x 128 u16 = 4 KB
    #pragma unroll
    for (int r = 0; r < 4; ++r) {
        const int rw = gq * 4 + r;
        st[rw * 128 + c0] = f2bf(fmaxf(a0[r] + b0, 0.f));
        st[rw * 128 + c1] = f2bf(fmaxf(a1[r] + b1, 0.f));
    }
    __syncthreads();
    uint4* dst = (uint4*)(h_out + (size_t)nb * 128);
    dst[tid] = ((const uint4*)st)[tid];
}

// ---------------- fused SAGE layer (MFMA, TNL=32) + optional fused heads --
template<int LAST>
__global__ __launch_bounds__(256, 8)
void sage_layer_kernel(const u16* __restrict__ h_in,
                       u16* __restrict__ h_out_bf, float* __restrict__ o_h,
                       const u16* __restrict__ wlfrag, const float* __restrict__ bl,
                       const u16* __restrict__ wrfrag,
                       const float* __restrict__ bn_g, const float* __restrict__ bn_b,
                       const float* __restrict__ bn_m, const float* __restrict__ bn_v,
                       const int* __restrict__ row_ptr, const int* __restrict__ csr_src,
                       const float* __restrict__ inv_deg,
                       const u16* __restrict__ o1frag, const float* __restrict__ ob1,
                       const float* __restrict__ ow2, const float* __restrict__ ob2,
                       const u16* __restrict__ c1frag, const float* __restrict__ cb1,
                       const float* __restrict__ cw2, const float* __restrict__ cb2,
                       const u16* __restrict__ b1frag, const float* __restrict__ bb1,
                       const float* __restrict__ bw2, const float* __restrict__ bb2,
                       float* __restrict__ o_order, float* __restrict__ o_cost,
                       float* __restrict__ o_bw) {
    __shared__ uint4 sRows[512];   // 32 rows x 16 chunks, swizzled (8 KB)
    __shared__ uint4 sMean[512];   // 8 KB
    __shared__ float ssb[4][32];
    const int tid = threadIdx.x;
    const int nb = blockIdx.x * TNL;

    // stage h rows (bf16 passthrough, swizzled): 512 uint4
    {
        const uint4* src = (const uint4*)h_in + (size_t)nb * 16;
        const int i0 = tid, i1 = tid + 256;
        sRows[(i0 >> 4) * 16 + ((i0 & 15) ^ ((i0 >> 4) & 7))] = src[i0];
        sRows[(i1 >> 4) * 16 + ((i1 & 15) ^ ((i1 >> 4) & 7))] = src[i1];
    }

    // gather neighbor mean: 16-lane group serves nodes g and g+16 with
    // INTERLEAVED edge loops -> 8 independent row loads in flight per lane
    {
        const int g = tid >> 4, t = tid & 15;
        const uint4* hb = (const uint4*)h_in;
        const int nA = nb + g, nB = nb + g + 16;
        float accA[8] = {0, 0, 0, 0, 0, 0, 0, 0};
        float accB[8] = {0, 0, 0, 0, 0, 0, 0, 0};
        const int rpA0 = row_ptr[nA], rpA1 = row_ptr[nA + 1];
        const int rpB0 = row_ptr[nB], rpB1 = row_ptr[nB + 1];
        int ea = rpA0, eb = rpB0;
        // interleaved main loop: 4 loads per node in flight simultaneously
        while (ea + 3 < rpA1 && eb + 3 < rpB1) {
            const int ia0 = csr_src[ea],     ia1 = csr_src[ea + 1];
            const int ia2 = csr_src[ea + 2], ia3 = csr_src[ea + 3];
            const int ib0 = csr_src[eb],     ib1 = csr_src[eb + 1];
            const int ib2 = csr_src[eb + 2], ib3 = csr_src[eb + 3];
            const uint4 va0 = hb[(size_t)ia0 * 16 + t];
            const uint4 va1 = hb[(size_t)ia1 * 16 + t];
            const uint4 va2 = hb[(size_t)ia2 * 16 + t];
            const uint4 va3 = hb[(size_t)ia3 * 16 + t];
            const uint4 vb0 = hb[(size_t)ib0 * 16 + t];
            const uint4 vb1 = hb[(size_t)ib1 * 16 + t];
            const uint4 vb2 = hb[(size_t)ib2 * 16 + t];
            const uint4 vb3 = hb[(size_t)ib3 * 16 + t];
            acc8(accA, va0); acc8(accA, va1); acc8(accA, va2); acc8(accA, va3);
            acc8(accB, vb0); acc8(accB, vb1); acc8(accB, vb2); acc8(accB, vb3);
            ea += 4; eb += 4;
        }
        // drain node A
        for (; ea + 3 < rpA1; ea += 4) {
            const int i0 = csr_src[ea],     i1 = csr_src[ea + 1];
            const int i2 = csr_src[ea + 2], i3 = csr_src[ea + 3];
            const uint4 v0 = hb[(size_t)i0 * 16 + t];
            const uint4 v1 = hb[(size_t)i1 * 16 + t];
            const uint4 v2 = hb[(size_t)i2 * 16 + t];
            const uint4 v3 = hb[(size_t)i3 * 16 + t];
            acc8(accA, v0); acc8(accA, v1); acc8(accA, v2); acc8(accA, v3);
        }
        for (; ea < rpA1; ++ea) acc8(accA, hb[(size_t)csr_src[ea] * 16 + t]);
        // drain node B
        for (; eb + 3 < rpB1; eb += 4) {
            const int i0 = csr_src[eb],     i1 = csr_src[eb + 1];
            const int i2 = csr_src[eb + 2], i3 = csr_src[eb + 3];
            const uint4 v0 = hb[(size_t)i0 * 16 + t];
            const uint4 v1 = hb[(size_t)i1 * 16 + t];
            const uint4 v2 = hb[(size_t)i2 * 16 + t];
            const uint4 v3 = hb[(size_t)i3 * 16 + t];
            acc8(accB, v0); acc8(accB, v1); acc8(accB, v2); acc8(accB, v3);
        }
        for (; eb < rpB1; ++eb) acc8(accB, hb[(size_t)csr_src[eb] * 16 + t]);

        const float idA = inv_deg[nA], idB = inv_deg[nB];
        uint4 mpA, mpB;
        mpA.x = packbf(accA[0] * idA, accA[1] * idA);
        mpA.y = packbf(accA[2] * idA, accA[3] * idA);
        mpA.z = packbf(accA[4] * idA, accA[5] * idA);
        mpA.w = packbf(accA[6] * idA, accA[7] * idA);
        mpB.x = packbf(accB[0] * idB, accB[1] * idB);
        mpB.y = packbf(accB[2] * idB, accB[3] * idB);
        mpB.z = packbf(accB[4] * idB, accB[5] * idB);
        mpB.w = packbf(accB[6] * idB, accB[7] * idB);
        sMean[g * 16 + (t ^ (g & 7))] = mpA;
        sMean[(g + 16) * 16 + (t ^ ((g + 16) & 7))] = mpB;
    }
    __syncthreads();

    const int lane = tid & 63, wave = tid >> 6;
    const int cl = lane & 15, gq = lane >> 4;
    const int jt0 = wave * 2, jt1 = wave * 2 + 1;
    f32x4 a00 = {0,0,0,0}, a01 = {0,0,0,0}, a10 = {0,0,0,0}, a11 = {0,0,0,0};
    {
        const uint4* wf = (const uint4*)wlfrag;
        #pragma unroll
        for (int kk = 0; kk < 4; ++kk) {
            const int ch = (kk * 4 + gq) ^ (cl & 7);
            const uint4 af0 = sMean[cl * 16 + ch];
            const uint4 af1 = sMean[(16 + cl) * 16 + ch];
            const uint4 b0 = wf[(jt0 * 4 + kk) * 64 + lane];
            const uint4 b1 = wf[(jt1 * 4 + kk) * 64 + lane];
            a00 = mfma16(af0, b0, a00); a01 = mfma16(af0, b1, a01);
            a10 = mfma16(af1, b0, a10); a11 = mfma16(af1, b1, a11);
        }
    }
    {
        const uint4* wf = (const uint4*)wrfrag;
        #pragma unroll
        for (int kk = 0; kk < 4; ++kk) {
            const int ch = (kk * 4 + gq) ^ (cl & 7);
            const uint4 af0 = sRows[cl * 16 + ch];
            const uint4 af1 = sRows[(16 + cl) * 16 + ch];
            const uint4 b0 = wf[(jt0 * 4 + kk) * 64 + lane];
            const uint4 b1 = wf[(jt1 * 4 + kk) * 64 + lane];
            a00 = mfma16(af0, b0, a00); a01 = mfma16(af0, b1, a01);
            a10 = mfma16(af1, b0, a10); a11 = mfma16(af1, b1, a11);
        }
    }

    // epilogue: +bias, row L2-norm (cross-wave), BN(eval), relu
    const int c0 = jt0 * 16 + cl, c1 = jt1 * 16 + cl;
    const float bl0 = bl[c0], bl1 = bl[c1];
    float t00[4], t01[4], t10[4], t11[4], ss0[4], ss1[4];
    #pragma unroll
    for (int r = 0; r < 4; ++r) {
        t00[r] = a00[r] + bl0; t01[r] = a01[r] + bl1;
        t10[r] = a10[r] + bl0; t11[r] = a11[r] + bl1;
        ss0[r] = t00[r] * t00[r] + t01[r] * t01[r];
        ss1[r] = t10[r] * t10[r] + t11[r] * t11[r];
    }
    #pragma unroll
    for (int m = 1; m <= 8; m <<= 1) {
        #pragma unroll
        for (int r = 0; r < 4; ++r) {
            ss0[r] += __shfl_xor(ss0[r], m);
            ss1[r] += __shfl_xor(ss1[r], m);
        }
    }
    if (cl == 0) {
        #pragma unroll
        for (int r = 0; r < 4; ++r) {
            ssb[wave][gq * 4 + r] = ss0[r];
            ssb[wave][16 + gq * 4 + r] = ss1[r];
        }
    }
    __syncthreads();   // also guarantees all MFMA reads of sMean/sRows are done

    const float sc0 = bn_g[c0] * rsqrtf(bn_v[c0] + BN_EPS);
    const float sc1 = bn_g[c1] * rsqrtf(bn_v[c1] + BN_EPS);
    const float m0 = bn_m[c0], m1 = bn_m[c1];
    const float bb0 = bn_b[c0], bb1v = bn_b[c1];
    float f00[4], f01[4], f10[4], f11[4];
    #pragma unroll
    for (int r = 0; r < 4; ++r) {
        const int rw0 = gq * 4 + r, rw1 = 16 + rw0;
        const float tot0 = ssb[0][rw0] + ssb[1][rw0] + ssb[2][rw0] + ssb[3][rw0];
        const float tot1 = ssb[0][rw1] + ssb[1][rw1] + ssb[2][rw1] + ssb[3][rw1];
        const float inv0 = 1.0f / fmaxf(sqrtf(tot0), NORM_EPS);
        const float inv1 = 1.0f / fmaxf(sqrtf(tot1), NORM_EPS);
        f00[r] = fmaxf((t00[r] * inv0 - m0) * sc0 + bb0, 0.f);
        f01[r] = fmaxf((t01[r] * inv0 - m1) * sc1 + bb1v, 0.f);
        f10[r] = fmaxf((t10[r] * inv1 - m0) * sc0 + bb0, 0.f);
        f11[r] = fmaxf((t11[r] * inv1 - m1) * sc1 + bb1v, 0.f);
    }

    if (!LAST) {
        // stage bf16 output in LDS (sMean is dead) -> coalesced stores
        u16* st = (u16*)sMean;   // 32 rows x 128 u16 = 8 KB
        #pragma unroll
        for (int r = 0; r < 4; ++r) {
            const int rw0 = gq * 4 + r, rw1 = 16 + rw0;
            st[rw0 * 128 + c0] = f2bf(f00[r]);
            st[rw0 * 128 + c1] = f2bf(f01[r]);
            st[rw1 * 128 + c0] = f2bf(f10[r]);
            st[rw1 * 128 + c1] = f2bf(f11[r]);
        }
        __syncthreads();
        uint4* dst = (uint4*)(h_out_bf + (size_t)nb * 128);
        dst[tid] = ((const uint4*)st)[tid];
        dst[tid + 256] = ((const uint4*)st)[tid + 256];
        return;
    }

    // LAST: o_h f32 via two staged passes (sMean as float[16][128] = 8 KB)
    {
        float* stf = (float*)sMean;
        #pragma unroll
        for (int r = 0; r < 4; ++r) {
            const int rw0 = gq * 4 + r;
            stf[rw0 * 128 + c0] = f00[r];
            stf[rw0 * 128 + c1] = f01[r];
        }
        __syncthreads();
        float4* dst0 = (float4*)(o_h + (size_t)nb * 128);
        dst0[tid] = ((const float4*)stf)[tid];
        dst0[tid + 256] = ((const float4*)stf)[tid + 256];
        __syncthreads();
        #pragma unroll
        for (int r = 0; r < 4; ++r) {
            const int rw0 = gq * 4 + r;
            stf[rw0 * 128 + c0] = f10[r];
            stf[rw0 * 128 + c1] = f11[r];
        }
        __syncthreads();
        float4* dst1 = (float4*)(o_h + (size_t)(nb + 16) * 128);
        dst1[tid] = ((const float4*)stf)[tid];
        dst1[tid + 256] = ((const float4*)stf)[tid + 256];
    }

    // restage bf16 h into sRows for fused heads
    u16* sr16 = (u16*)sRows;
    #pragma unroll
    for (int r = 0; r < 4; ++r) {
        const int rw0 = gq * 4 + r, rw1 = 16 + rw0;
        sr16[rw0 * 128 + (((c0 >> 3) ^ (rw0 & 7)) << 3) + (c0 & 7)] = f2bf(f00[r]);
        sr16[rw0 * 128 + (((c1 >> 3) ^ (rw0 & 7)) << 3) + (c1 & 7)] = f2bf(f01[r]);
        sr16[rw1 * 128 + (((c0 >> 3) ^ (rw1 & 7)) << 3) + (c0 & 7)] = f2bf(f10[r]);
        sr16[rw1 * 128 + (((c1 >> 3) ^ (rw1 & 7)) << 3) + (c1 & 7)] = f2bf(f11[r]);
    }
    __syncthreads();

    // ---- order head: hidden 128, then dot with ow2 ----
    {
        const uint4* wf = (const uint4*)o1frag;
        f32x4 h00 = {0,0,0,0}, h01 = {0,0,0,0}, h10 = {0,0,0,0}, h11 = {0,0,0,0};
        #pragma unroll
        for (int kk = 0; kk < 4; ++kk) {
            const int ch = (kk * 4 + gq) ^ (cl & 7);
            const uint4 af0 = sRows[cl * 16 + ch];
            const uint4 af1 = sRows[(16 + cl) * 16 + ch];
            const uint4 b0 = wf[(jt0 * 4 + kk) * 64 + lane];
            const uint4 b1 = wf[(jt1 * 4 + kk) * 64 + lane];
            h00 = mfma16(af0, b0, h00); h01 = mfma16(af0, b1, h01);
            h10 = mfma16(af1, b0, h10); h11 = mfma16(af1, b1, h11);
        }
        const float hb0 = ob1[c0], hb1 = ob1[c1];
        const float w20 = ow2[c0], w21 = ow2[c1];
        float p0[4], p1[4];
        #pragma unroll
        for (int r = 0; r < 4; ++r) {
            p0[r] = fmaxf(h00[r] + hb0, 0.f) * w20 + fmaxf(h01[r] + hb1, 0.f) * w21;
            p1[r] = fmaxf(h10[r] + hb0, 0.f) * w20 + fmaxf(h11[r] + hb1, 0.f) * w21;
        }
        #pragma unroll
        for (int m = 1; m <= 8; m <<= 1) {
            #pragma unroll
            for (int r = 0; r < 4; ++r) {
                p0[r] += __shfl_xor(p0[r], m);
                p1[r] += __shfl_xor(p1[r], m);
            }
        }
        if (cl == 0) {
            #pragma unroll
            for (int r = 0; r < 4; ++r) {
                ssb[wave][gq * 4 + r] = p0[r];
                ssb[wave][16 + gq * 4 + r] = p1[r];
            }
        }
        __syncthreads();
        if (tid < 32)
            o_order[nb + tid] = ssb[0][tid] + ssb[1][tid] + ssb[2][tid] + ssb[3][tid] + ob2[0];
        __syncthreads();
    }

    // ---- cost / bullwhip heads: hidden 64 (one 16-col tile per wave) ----
    const u16* hfr[2] = {c1frag, b1frag};
    const float* hb1a[2] = {cb1, bb1};
    const float* hw2a[2] = {cw2, bw2};
    const float* hb2a[2] = {cb2, bb2};
    float* outs[2] = {o_cost, o_bw};
    #pragma unroll
    for (int ph = 0; ph < 2; ++ph) {
        const uint4* wf = (const uint4*)hfr[ph];
        f32x4 g0 = {0,0,0,0}, g1 = {0,0,0,0};
        #pragma unroll
        for (int kk = 0; kk < 4; ++kk) {
            const int ch = (kk * 4 + gq) ^ (cl & 7);
            const uint4 af0 = sRows[cl * 16 + ch];
            const uint4 af1 = sRows[(16 + cl) * 16 + ch];
            const uint4 b = wf[(wave * 4 + kk) * 64 + lane];
            g0 = mfma16(af0, b, g0);
            g1 = mfma16(af1, b, g1);
        }
        const int cc = wave * 16 + cl;
        const float hb = hb1a[ph][cc], w2 = hw2a[ph][cc];
        float p0[4], p1[4];
        #pragma unroll
        for (int r = 0; r < 4; ++r) {
            p0[r] = fmaxf(g0[r] + hb, 0.f) * w2;
            p1[r] = fmaxf(g1[r] + hb, 0.f) * w2;
        }
        #pragma unroll
        for (int m = 1; m <= 8; m <<= 1) {
            #pragma unroll
            for (int r = 0; r < 4; ++r) {
                p0[r] += __shfl_xor(p0[r], m);
                p1[r] += __shfl_xor(p1[r], m);
            }
        }
        if (cl == 0) {
            #pragma unroll
            for (int r = 0; r < 4; ++r) {
                ssb[wave][gq * 4 + r] = p0[r];
                ssb[wave][16 + gq * 4 + r] = p1[r];
            }
        }
        __syncthreads();
        if (tid < 32)
            outs[ph][nb + tid] = ssb[0][tid] + ssb[1][tid] + ssb[2][tid] + ssb[3][tid] + hb2a[ph][0];
        __syncthreads();
    }
}

extern "C" void kernel_launch(void* const* d_in, const int* in_sizes, int n_in,
                              void* d_out, int out_size, void* d_ws, size_t ws_size,
                              hipStream_t stream) {
    (void)in_sizes; (void)n_in; (void)out_size;

    const float* x       = (const float*)d_in[0];
    const int*   ei      = (const int*)d_in[1];
    const float* enc_w   = (const float*)d_in[2];
    const float* enc_b   = (const float*)d_in[3];
    const float* ll_w    = (const float*)d_in[4];
    const float* ll_b    = (const float*)d_in[5];
    const float* lr_w    = (const float*)d_in[6];
    const float* bn_g    = (const float*)d_in[7];
    const float* bn_b    = (const float*)d_in[8];
    const float* bn_m    = (const float*)d_in[9];
    const float* bn_v    = (const float*)d_in[10];
    const float* out_w1  = (const float*)d_in[11];
    const float* out_b1  = (const float*)d_in[12];
    const float* out_w2  = (const float*)d_in[13];
    const float* out_b2  = (const float*)d_in[14];
    const float* cost_w1 = (const float*)d_in[15];
    const float* cost_b1 = (const float*)d_in[16];
    const float* cost_w2 = (const float*)d_in[17];
    const float* cost_b2 = (const float*)d_in[18];
    const float* bw_w1   = (const float*)d_in[19];
    const float* bw_b1   = (const float*)d_in[20];
    const float* bw_w2   = (const float*)d_in[21];
    const float* bw_b2   = (const float*)d_in[22];

    const int* e_src = ei;
    const int* e_dst = ei + NE;

    float* o_order = (float*)d_out;
    float* o_cost  = o_order + NN;
    float* o_bw    = o_cost + NN;
    float* o_h     = o_bw + NN;   // NN*128 f32 (final h)

    // workspace layout
    u16* hA = (u16*)d_ws;                       // NN*128 bf16
    u16* hB = hA + (size_t)NN * 128;            // NN*128 bf16
    u16* wt = hB + (size_t)NN * 128;            // 147456 bf16 (fragment layout)
    u16* wt_enc  = wt;
    u16* wt_ll   = wt + 16384;
    u16* wt_lr   = wt + 16384 * 4;
    u16* wt_out1 = wt + 16384 * 7;
    u16* wt_c1   = wt + 16384 * 8;
    u16* wt_bw1  = wt + 16384 * 8 + 8192;
    int* row_ptr  = (int*)(wt + 147456);        // NN+1 (+pad)
    float* inv_deg = (float*)(row_ptr + NN + 4);
    int* csr_src  = (int*)(inv_deg + NN);       // NE
    int* bcnt     = csr_src + NE;               // NBK+1
    int* bbase    = bcnt + NBK + 1;             // NBK+1
    u32* ebuf     = (u32*)(bbase + NBK + 1);    // NBK*BCAP

    const size_t need = (size_t)((char*)(ebuf + (size_t)NBK * BCAP) - (char*)d_ws);
    if (ws_size < need) return;

    (void)hipMemsetAsync(bcnt, 0, (NBK + 1) * sizeof(int), stream);

    TposeArgs ta;
    ta.src[0] = enc_w;          ta.dst[0] = wt_enc;          ta.rows[0] = 128;
    ta.src[1] = ll_w;           ta.dst[1] = wt_ll;           ta.rows[1] = 128;
    ta.src[2] = ll_w + 16384;   ta.dst[2] = wt_ll + 16384;   ta.rows[2] = 128;
    ta.src[3] = ll_w + 32768;   ta.dst[3] = wt_ll + 32768;   ta.rows[3] = 128;
    ta.src[4] = lr_w;           ta.dst[4] = wt_lr;           ta.rows[4] = 128;
    ta.src[5] = lr_w + 16384;   ta.dst[5] = wt_lr + 16384;   ta.rows[5] = 128;
    ta.src[6] = lr_w + 32768;   ta.dst[6] = wt_lr + 32768;   ta.rows[6] = 128;
    ta.src[7] = out_w1;         ta.dst[7] = wt_out1;         ta.rows[7] = 128;
    ta.src[8] = cost_w1;        ta.dst[8] = wt_c1;           ta.rows[8] = 64;
    ta.src[9] = bw_w1;          ta.dst[9] = wt_bw1;          ta.rows[9] = 64;
    frag_kernel<<<10, 256, 0, stream>>>(ta);

    bucket_scatter_kernel<<<(NE + CTILE - 1) / CTILE, 256, 0, stream>>>(e_src, e_dst, bcnt, ebuf);
    bscan_kernel<<<1, 64, 0, stream>>>(bcnt, bbase);
    csr_finalize_kernel<<<NBK, 256, 0, stream>>>(ebuf, bcnt, bbase, row_ptr, inv_deg, csr_src);

    encoder_kernel<<<NN / TN, 256, 0, stream>>>(x, hA, wt_enc, enc_b);
    sage_layer_kernel<0><<<NN / TNL, 256, 0, stream>>>(hA, hB, nullptr, wt_ll, ll_b, wt_lr,
        bn_g, bn_b, bn_m, bn_v, row_ptr, csr_src, inv_deg,
        nullptr, nullptr, nullptr, nullptr, nullptr, nullptr, nullptr, nullptr,
        nullptr, nullptr, nullptr, nullptr, nullptr, nullptr, nullptr);
    sage_layer_kernel<0><<<NN / TNL, 256, 0, stream>>>(hB, hA, nullptr, wt_ll + 16384, ll_b + 128, wt_lr + 16384,
        bn_g + 128, bn_b + 128, bn_m + 128, bn_v + 128, row_ptr, csr_src, inv_deg,
        nullptr, nullptr, nullptr, nullptr, nullptr, nullptr, nullptr, nullptr,
        nullptr, nullptr, nullptr, nullptr, nullptr, nullptr, nullptr);
    sage_layer_kernel<1><<<NN / TNL, 256, 0, stream>>>(hA, nullptr, o_h, wt_ll + 32768, ll_b + 256, wt_lr + 32768,
        bn_g + 256, bn_b + 256, bn_m + 256, bn_v + 256, row_ptr, csr_src, inv_deg,
        wt_out1, out_b1, out_w2, out_b2,
        wt_c1, cost_b1, cost_w2, cost_b2,
        wt_bw1, bw_b1, bw_w2, bw_b2,
        o_order, o_cost, o_bw);
}

// Round 12
// 312.312 us; speedup vs baseline: 1.2368x; 1.1969x over previous
//
#include <hip/hip_runtime.h>

#define NN 100000
#define NE 1600000
#define TN 16        // encoder tile
#define TNL 32       // sage-layer tile
#define NBK 391      // ceil(NN/256) buckets of 256 nodes
#define BCAP 5120    // per-bucket edge capacity (mean 4096)
#define CTILE 8192   // edges per workgroup in bucket_scatter

static constexpr float BN_EPS = 1e-5f;
static constexpr float NORM_EPS = 1e-12f;

typedef unsigned int u32;
typedef unsigned short u16;
typedef __attribute__((ext_vector_type(8))) short short8;
typedef __attribute__((ext_vector_type(4))) float f32x4;

// ---------------- bf16 helpers ----------------
__device__ __forceinline__ float bflo(u32 u) {
    u32 v = u << 16; float f; __builtin_memcpy(&f, &v, 4); return f;
}
__device__ __forceinline__ float bfhi(u32 u) {
    u32 v = u & 0xffff0000u; float f; __builtin_memcpy(&f, &v, 4); return f;
}
__device__ __forceinline__ u32 packbf(float a, float b) {
    u32 ua, ub; __builtin_memcpy(&ua, &a, 4); __builtin_memcpy(&ub, &b, 4);
    u32 ra = (ua + 0x7fffu + ((ua >> 16) & 1u)) >> 16;
    u32 rb = (ub + 0x7fffu + ((ub >> 16) & 1u)) & 0xffff0000u;
    return ra | rb;
}
__device__ __forceinline__ u16 f2bf(float a) {
    u32 ua; __builtin_memcpy(&ua, &a, 4);
    return (u16)((ua + 0x7fffu + ((ua >> 16) & 1u)) >> 16);
}
__device__ __forceinline__ void acc8(float* s, uint4 v) {
    s[0] += bflo(v.x); s[1] += bfhi(v.x);
    s[2] += bflo(v.y); s[3] += bfhi(v.y);
    s[4] += bflo(v.z); s[5] += bfhi(v.z);
    s[6] += bflo(v.w); s[7] += bfhi(v.w);
}
__device__ __forceinline__ f32x4 mfma16(uint4 a, uint4 b, f32x4 c) {
    return __builtin_amdgcn_mfma_f32_16x16x32_bf16(
        __builtin_bit_cast(short8, a), __builtin_bit_cast(short8, b), c, 0, 0, 0);
}

// ------------- weight fragmentize: W[J][128] f32 -> MFMA B-frag bf16 -------
struct TposeArgs {
    const float* src[10];
    u16* dst[10];
    int rows[10];
};

__global__ void frag_kernel(TposeArgs a) {
    const int m = blockIdx.x;
    const float* __restrict__ s = a.src[m];
    u16* __restrict__ d = a.dst[m];
    const int total = a.rows[m] * 128;
    for (int idx = threadIdx.x; idx < total; idx += 256) {
        const int i = idx & 7;
        const int l = (idx >> 3) & 63;
        const int kk = (idx >> 9) & 3;
        const int jt = idx >> 11;
        const int j = jt * 16 + (l & 15);
        const int k = kk * 32 + ((l >> 4) << 3) + i;
        d[idx] = f2bf(s[j * 128 + k]);
    }
}

// ---------------- CSR build: bucketed, LDS-amortized ----------------
__global__ __launch_bounds__(256, 4)
void bucket_scatter_kernel(const int* __restrict__ e_src, const int* __restrict__ e_dst,
                           int* __restrict__ bcnt, u32* __restrict__ ebuf) {
    __shared__ int h[NBK];
    const int tid = threadIdx.x;
    const int base = blockIdx.x * CTILE;
    const int end = (base + CTILE < NE) ? base + CTILE : NE;
    for (int i = tid; i < NBK; i += 256) h[i] = 0;
    __syncthreads();
    for (int e = base + tid; e < end; e += 256)
        atomicAdd(&h[e_dst[e] >> 8], 1);
    __syncthreads();
    for (int i = tid; i < NBK; i += 256) {
        const int c = h[i];
        h[i] = (c > 0) ? atomicAdd(&bcnt[i], c) : 0;
    }
    __syncthreads();
    for (int e = base + tid; e < end; e += 256) {
        const int d = e_dst[e];
        const int b = d >> 8;
        const int slot = atomicAdd(&h[b], 1);
        if (slot < BCAP)
            ebuf[(size_t)b * BCAP + slot] = (u32)e_src[e] | ((u32)(d & 255) << 17);
    }
}

__global__ void bscan_kernel(const int* __restrict__ bcnt, int* __restrict__ bbase) {
    const int lane = threadIdx.x;   // 64 threads
    const int per = (NBK + 63) / 64;
    int vals[8];
    int s = 0;
    for (int i = 0; i < per; ++i) {
        const int idx = lane * per + i;
        const int v = (idx < NBK) ? bcnt[idx] : 0;
        vals[i] = s; s += v;
    }
    int incl = s;
    for (int off = 1; off < 64; off <<= 1) {
        const int t = __shfl_up(incl, off);
        if (lane >= off) incl += t;
    }
    const int excl = incl - s;
    for (int i = 0; i < per; ++i) {
        const int idx = lane * per + i;
        if (idx < NBK) bbase[idx] = excl + vals[i];
    }
    if (lane == 63) bbase[NBK] = excl + s;
}

__global__ __launch_bounds__(256, 4)
void csr_finalize_kernel(const u32* __restrict__ ebuf, const int* __restrict__ bcnt,
                         const int* __restrict__ bbase,
                         int* __restrict__ row_ptr, float* __restrict__ inv_deg,
                         int* __restrict__ csr_src) {
    __shared__ int cnt[256];
    __shared__ int rc[256];
    const int b = blockIdx.x;
    const int tid = threadIdx.x;
    const int n0 = b << 8;
    const int nb_nodes = (NN - n0 < 256) ? NN - n0 : 256;
    int ecnt = bcnt[b];
    if (ecnt > BCAP) ecnt = BCAP;
    const int gbase = bbase[b];
    const u32* eb = ebuf + (size_t)b * BCAP;
    cnt[tid] = 0;
    __syncthreads();
    for (int e = tid; e < ecnt; e += 256)
        atomicAdd(&cnt[eb[e] >> 17], 1);
    __syncthreads();
    const int myc = cnt[tid];
    int val = myc;
    for (int off = 1; off < 256; off <<= 1) {
        const int t = (tid >= off) ? cnt[tid - off] : 0;
        __syncthreads();
        val += t;
        cnt[tid] = val;
        __syncthreads();
    }
    const int excl = val - myc;
    if (tid < nb_nodes) {
        row_ptr[n0 + tid] = gbase + excl;
        inv_deg[n0 + tid] = 1.0f / (float)(myc < 1 ? 1 : myc);
    }
    rc[tid] = gbase + excl;
    __syncthreads();
    for (int e = tid; e < ecnt; e += 256) {
        const u32 p = eb[e];
        const int pos = atomicAdd(&rc[p >> 17], 1);
        csr_src[pos] = (int)(p & 0x1FFFFu);
    }
    if (b == NBK - 1 && tid == 0) row_ptr[NN] = NE;
}

// ---------------- encoder: h = relu(x @ W^T + b) via MFMA, bf16 out -------
__global__ __launch_bounds__(256, 6)
void encoder_kernel(const float* __restrict__ x, u16* __restrict__ h_out,
                    const u16* __restrict__ wfrag, const float* __restrict__ bias) {
    __shared__ uint4 sRows[256];
    const int tid = threadIdx.x;
    const int nb = blockIdx.x * TN;

    {
        const int row = tid >> 4, t = tid & 15;
        const float4* xr = (const float4*)(x + (size_t)(nb + row) * 128 + t * 8);
        const float4 xa = xr[0], xb = xr[1];
        uint4 p;
        p.x = packbf(xa.x, xa.y); p.y = packbf(xa.z, xa.w);
        p.z = packbf(xb.x, xb.y); p.w = packbf(xb.z, xb.w);
        sRows[row * 16 + (t ^ (row & 7))] = p;
    }
    __syncthreads();

    const int lane = tid & 63, wave = tid >> 6;
    const int cl = lane & 15, gq = lane >> 4;
    const int jt0 = wave * 2, jt1 = wave * 2 + 1;
    const uint4* wf = (const uint4*)wfrag;
    f32x4 a0 = {0, 0, 0, 0}, a1 = {0, 0, 0, 0};
    #pragma unroll
    for (int kk = 0; kk < 4; ++kk) {
        const uint4 af = sRows[cl * 16 + ((kk * 4 + gq) ^ (cl & 7))];
        a0 = mfma16(af, wf[(jt0 * 4 + kk) * 64 + lane], a0);
        a1 = mfma16(af, wf[(jt1 * 4 + kk) * 64 + lane], a1);
    }
    const int c0 = jt0 * 16 + cl, c1 = jt1 * 16 + cl;
    const float b0 = bias[c0], b1 = bias[c1];
    __syncthreads();   // all MFMA reads of sRows done; reuse as store stage
    u16* st = (u16*)sRows;   // 16 rows x 128 u16 = 4 KB
    #pragma unroll
    for (int r = 0; r < 4; ++r) {
        const int rw = gq * 4 + r;
        st[rw * 128 + c0] = f2bf(fmaxf(a0[r] + b0, 0.f));
        st[rw * 128 + c1] = f2bf(fmaxf(a1[r] + b1, 0.f));
    }
    __syncthreads();
    uint4* dst = (uint4*)(h_out + (size_t)nb * 128);
    dst[tid] = ((const uint4*)st)[tid];
}

// ---------------- fused SAGE layer (MFMA, TNL=32) + optional fused heads --
template<int LAST>
__global__ __launch_bounds__(256, 8)
void sage_layer_kernel(const u16* __restrict__ h_in,
                       u16* __restrict__ h_out_bf, float* __restrict__ o_h,
                       const u16* __restrict__ wlfrag, const float* __restrict__ bl,
                       const u16* __restrict__ wrfrag,
                       const float* __restrict__ bn_g, const float* __restrict__ bn_b,
                       const float* __restrict__ bn_m, const float* __restrict__ bn_v,
                       const int* __restrict__ row_ptr, const int* __restrict__ csr_src,
                       const float* __restrict__ inv_deg,
                       const u16* __restrict__ o1frag, const float* __restrict__ ob1,
                       const float* __restrict__ ow2, const float* __restrict__ ob2,
                       const u16* __restrict__ c1frag, const float* __restrict__ cb1,
                       const float* __restrict__ cw2, const float* __restrict__ cb2,
                       const u16* __restrict__ b1frag, const float* __restrict__ bb1,
                       const float* __restrict__ bw2, const float* __restrict__ bb2,
                       float* __restrict__ o_order, float* __restrict__ o_cost,
                       float* __restrict__ o_bw) {
    __shared__ uint4 sRows[512];   // 32 rows x 16 chunks, swizzled (8 KB)
    __shared__ uint4 sMean[512];   // 8 KB
    __shared__ float ssb[4][32];
    const int tid = threadIdx.x;
    const int nb = blockIdx.x * TNL;

    // stage h rows (bf16 passthrough, swizzled): 512 uint4
    {
        const uint4* src = (const uint4*)h_in + (size_t)nb * 16;
        const int i0 = tid, i1 = tid + 256;
        sRows[(i0 >> 4) * 16 + ((i0 & 15) ^ ((i0 >> 4) & 7))] = src[i0];
        sRows[(i1 >> 4) * 16 + ((i1 & 15) ^ ((i1 >> 4) & 7))] = src[i1];
    }

    // gather neighbor mean: 16-lane group serves 2 nodes (g, g+16), unroll-4
    {
        const int g = tid >> 4, t = tid & 15;
        const uint4* hb = (const uint4*)h_in;
        #pragma unroll
        for (int half = 0; half < 2; ++half) {
            const int row = g + half * 16;
            const int n = nb + row;
            float acc[8] = {0, 0, 0, 0, 0, 0, 0, 0};
            const int rp0 = row_ptr[n], rp1 = row_ptr[n + 1];
            int e = rp0;
            for (; e + 3 < rp1; e += 4) {
                const int s0 = csr_src[e], s1 = csr_src[e + 1];
                const int s2 = csr_src[e + 2], s3 = csr_src[e + 3];
                const uint4 va = hb[(size_t)s0 * 16 + t];
                const uint4 vb = hb[(size_t)s1 * 16 + t];
                const uint4 vc = hb[(size_t)s2 * 16 + t];
                const uint4 vd = hb[(size_t)s3 * 16 + t];
                acc8(acc, va); acc8(acc, vb); acc8(acc, vc); acc8(acc, vd);
            }
            for (; e < rp1; ++e) acc8(acc, hb[(size_t)csr_src[e] * 16 + t]);
            const float id = inv_deg[n];
            uint4 mp;
            mp.x = packbf(acc[0] * id, acc[1] * id);
            mp.y = packbf(acc[2] * id, acc[3] * id);
            mp.z = packbf(acc[4] * id, acc[5] * id);
            mp.w = packbf(acc[6] * id, acc[7] * id);
            sMean[row * 16 + (t ^ (row & 7))] = mp;
        }
    }
    __syncthreads();

    const int lane = tid & 63, wave = tid >> 6;
    const int cl = lane & 15, gq = lane >> 4;
    const int jt0 = wave * 2, jt1 = wave * 2 + 1;
    f32x4 a00 = {0,0,0,0}, a01 = {0,0,0,0}, a10 = {0,0,0,0}, a11 = {0,0,0,0};
    {
        const uint4* wf = (const uint4*)wlfrag;
        #pragma unroll
        for (int kk = 0; kk < 4; ++kk) {
            const int ch = (kk * 4 + gq) ^ (cl & 7);
            const uint4 af0 = sMean[cl * 16 + ch];
            const uint4 af1 = sMean[(16 + cl) * 16 + ch];
            const uint4 b0 = wf[(jt0 * 4 + kk) * 64 + lane];
            const uint4 b1 = wf[(jt1 * 4 + kk) * 64 + lane];
            a00 = mfma16(af0, b0, a00); a01 = mfma16(af0, b1, a01);
            a10 = mfma16(af1, b0, a10); a11 = mfma16(af1, b1, a11);
        }
    }
    {
        const uint4* wf = (const uint4*)wrfrag;
        #pragma unroll
        for (int kk = 0; kk < 4; ++kk) {
            const int ch = (kk * 4 + gq) ^ (cl & 7);
            const uint4 af0 = sRows[cl * 16 + ch];
            const uint4 af1 = sRows[(16 + cl) * 16 + ch];
            const uint4 b0 = wf[(jt0 * 4 + kk) * 64 + lane];
            const uint4 b1 = wf[(jt1 * 4 + kk) * 64 + lane];
            a00 = mfma16(af0, b0, a00); a01 = mfma16(af0, b1, a01);
            a10 = mfma16(af1, b0, a10); a11 = mfma16(af1, b1, a11);
        }
    }

    // epilogue: +bias, row L2-norm (cross-wave), BN(eval), relu
    const int c0 = jt0 * 16 + cl, c1 = jt1 * 16 + cl;
    const float bl0 = bl[c0], bl1 = bl[c1];
    float t00[4], t01[4], t10[4], t11[4], ss0[4], ss1[4];
    #pragma unroll
    for (int r = 0; r < 4; ++r) {
        t00[r] = a00[r] + bl0; t01[r] = a01[r] + bl1;
        t10[r] = a10[r] + bl0; t11[r] = a11[r] + bl1;
        ss0[r] = t00[r] * t00[r] + t01[r] * t01[r];
        ss1[r] = t10[r] * t10[r] + t11[r] * t11[r];
    }
    #pragma unroll
    for (int m = 1; m <= 8; m <<= 1) {
        #pragma unroll
        for (int r = 0; r < 4; ++r) {
            ss0[r] += __shfl_xor(ss0[r], m);
            ss1[r] += __shfl_xor(ss1[r], m);
        }
    }
    if (cl == 0) {
        #pragma unroll
        for (int r = 0; r < 4; ++r) {
            ssb[wave][gq * 4 + r] = ss0[r];
            ssb[wave][16 + gq * 4 + r] = ss1[r];
        }
    }
    __syncthreads();   // also guarantees all MFMA reads of sMean/sRows are done

    const float sc0 = bn_g[c0] * rsqrtf(bn_v[c0] + BN_EPS);
    const float sc1 = bn_g[c1] * rsqrtf(bn_v[c1] + BN_EPS);
    const float m0 = bn_m[c0], m1 = bn_m[c1];
    const float bb0 = bn_b[c0], bb1v = bn_b[c1];
    float f00[4], f01[4], f10[4], f11[4];
    #pragma unroll
    for (int r = 0; r < 4; ++r) {
        const int rw0 = gq * 4 + r, rw1 = 16 + rw0;
        const float tot0 = ssb[0][rw0] + ssb[1][rw0] + ssb[2][rw0] + ssb[3][rw0];
        const float tot1 = ssb[0][rw1] + ssb[1][rw1] + ssb[2][rw1] + ssb[3][rw1];
        const float inv0 = 1.0f / fmaxf(sqrtf(tot0), NORM_EPS);
        const float inv1 = 1.0f / fmaxf(sqrtf(tot1), NORM_EPS);
        f00[r] = fmaxf((t00[r] * inv0 - m0) * sc0 + bb0, 0.f);
        f01[r] = fmaxf((t01[r] * inv0 - m1) * sc1 + bb1v, 0.f);
        f10[r] = fmaxf((t10[r] * inv1 - m0) * sc0 + bb0, 0.f);
        f11[r] = fmaxf((t11[r] * inv1 - m1) * sc1 + bb1v, 0.f);
    }

    if (!LAST) {
        // stage bf16 output in LDS (sMean is dead) -> coalesced stores
        u16* st = (u16*)sMean;   // 32 rows x 128 u16 = 8 KB
        #pragma unroll
        for (int r = 0; r < 4; ++r) {
            const int rw0 = gq * 4 + r, rw1 = 16 + rw0;
            st[rw0 * 128 + c0] = f2bf(f00[r]);
            st[rw0 * 128 + c1] = f2bf(f01[r]);
            st[rw1 * 128 + c0] = f2bf(f10[r]);
            st[rw1 * 128 + c1] = f2bf(f11[r]);
        }
        __syncthreads();
        uint4* dst = (uint4*)(h_out_bf + (size_t)nb * 128);
        dst[tid] = ((const uint4*)st)[tid];
        dst[tid + 256] = ((const uint4*)st)[tid + 256];
        return;
    }

    // LAST: o_h f32 via two staged passes (sMean as float[16][128] = 8 KB)
    {
        float* stf = (float*)sMean;
        #pragma unroll
        for (int r = 0; r < 4; ++r) {
            const int rw0 = gq * 4 + r;
            stf[rw0 * 128 + c0] = f00[r];
            stf[rw0 * 128 + c1] = f01[r];
        }
        __syncthreads();
        float4* dst0 = (float4*)(o_h + (size_t)nb * 128);
        dst0[tid] = ((const float4*)stf)[tid];
        dst0[tid + 256] = ((const float4*)stf)[tid + 256];
        __syncthreads();
        #pragma unroll
        for (int r = 0; r < 4; ++r) {
            const int rw0 = gq * 4 + r;
            stf[rw0 * 128 + c0] = f10[r];
            stf[rw0 * 128 + c1] = f11[r];
        }
        __syncthreads();
        float4* dst1 = (float4*)(o_h + (size_t)(nb + 16) * 128);
        dst1[tid] = ((const float4*)stf)[tid];
        dst1[tid + 256] = ((const float4*)stf)[tid + 256];
    }

    // restage bf16 h into sRows for fused heads
    u16* sr16 = (u16*)sRows;
    #pragma unroll
    for (int r = 0; r < 4; ++r) {
        const int rw0 = gq * 4 + r, rw1 = 16 + rw0;
        sr16[rw0 * 128 + (((c0 >> 3) ^ (rw0 & 7)) << 3) + (c0 & 7)] = f2bf(f00[r]);
        sr16[rw0 * 128 + (((c1 >> 3) ^ (rw0 & 7)) << 3) + (c1 & 7)] = f2bf(f01[r]);
        sr16[rw1 * 128 + (((c0 >> 3) ^ (rw1 & 7)) << 3) + (c0 & 7)] = f2bf(f10[r]);
        sr16[rw1 * 128 + (((c1 >> 3) ^ (rw1 & 7)) << 3) + (c1 & 7)] = f2bf(f11[r]);
    }
    __syncthreads();

    // ---- order head: hidden 128, then dot with ow2 ----
    {
        const uint4* wf = (const uint4*)o1frag;
        f32x4 h00 = {0,0,0,0}, h01 = {0,0,0,0}, h10 = {0,0,0,0}, h11 = {0,0,0,0};
        #pragma unroll
        for (int kk = 0; kk < 4; ++kk) {
            const int ch = (kk * 4 + gq) ^ (cl & 7);
            const uint4 af0 = sRows[cl * 16 + ch];
            const uint4 af1 = sRows[(16 + cl) * 16 + ch];
            const uint4 b0 = wf[(jt0 * 4 + kk) * 64 + lane];
            const uint4 b1 = wf[(jt1 * 4 + kk) * 64 + lane];
            h00 = mfma16(af0, b0, h00); h01 = mfma16(af0, b1, h01);
            h10 = mfma16(af1, b0, h10); h11 = mfma16(af1, b1, h11);
        }
        const float hb0 = ob1[c0], hb1 = ob1[c1];
        const float w20 = ow2[c0], w21 = ow2[c1];
        float p0[4], p1[4];
        #pragma unroll
        for (int r = 0; r < 4; ++r) {
            p0[r] = fmaxf(h00[r] + hb0, 0.f) * w20 + fmaxf(h01[r] + hb1, 0.f) * w21;
            p1[r] = fmaxf(h10[r] + hb0, 0.f) * w20 + fmaxf(h11[r] + hb1, 0.f) * w21;
        }
        #pragma unroll
        for (int m = 1; m <= 8; m <<= 1) {
            #pragma unroll
            for (int r = 0; r < 4; ++r) {
                p0[r] += __shfl_xor(p0[r], m);
                p1[r] += __shfl_xor(p1[r], m);
            }
        }
        if (cl == 0) {
            #pragma unroll
            for (int r = 0; r < 4; ++r) {
                ssb[wave][gq * 4 + r] = p0[r];
                ssb[wave][16 + gq * 4 + r] = p1[r];
            }
        }
        __syncthreads();
        if (tid < 32)
            o_order[nb + tid] = ssb[0][tid] + ssb[1][tid] + ssb[2][tid] + ssb[3][tid] + ob2[0];
        __syncthreads();
    }

    // ---- cost / bullwhip heads: hidden 64 (one 16-col tile per wave) ----
    const u16* hfr[2] = {c1frag, b1frag};
    const float* hb1a[2] = {cb1, bb1};
    const float* hw2a[2] = {cw2, bw2};
    const float* hb2a[2] = {cb2, bb2};
    float* outs[2] = {o_cost, o_bw};
    #pragma unroll
    for (int ph = 0; ph < 2; ++ph) {
        const uint4* wf = (const uint4*)hfr[ph];
        f32x4 g0 = {0,0,0,0}, g1 = {0,0,0,0};
        #pragma unroll
        for (int kk = 0; kk < 4; ++kk) {
            const int ch = (kk * 4 + gq) ^ (cl & 7);
            const uint4 af0 = sRows[cl * 16 + ch];
            const uint4 af1 = sRows[(16 + cl) * 16 + ch];
            const uint4 b = wf[(wave * 4 + kk) * 64 + lane];
            g0 = mfma16(af0, b, g0);
            g1 = mfma16(af1, b, g1);
        }
        const int cc = wave * 16 + cl;
        const float hb = hb1a[ph][cc], w2 = hw2a[ph][cc];
        float p0[4], p1[4];
        #pragma unroll
        for (int r = 0; r < 4; ++r) {
            p0[r] = fmaxf(g0[r] + hb, 0.f) * w2;
            p1[r] = fmaxf(g1[r] + hb, 0.f) * w2;
        }
        #pragma unroll
        for (int m = 1; m <= 8; m <<= 1) {
            #pragma unroll
            for (int r = 0; r < 4; ++r) {
                p0[r] += __shfl_xor(p0[r], m);
                p1[r] += __shfl_xor(p1[r], m);
            }
        }
        if (cl == 0) {
            #pragma unroll
            for (int r = 0; r < 4; ++r) {
                ssb[wave][gq * 4 + r] = p0[r];
                ssb[wave][16 + gq * 4 + r] = p1[r];
            }
        }
        __syncthreads();
        if (tid < 32)
            outs[ph][nb + tid] = ssb[0][tid] + ssb[1][tid] + ssb[2][tid] + ssb[3][tid] + hb2a[ph][0];
        __syncthreads();
    }
}

extern "C" void kernel_launch(void* const* d_in, const int* in_sizes, int n_in,
                              void* d_out, int out_size, void* d_ws, size_t ws_size,
                              hipStream_t stream) {
    (void)in_sizes; (void)n_in; (void)out_size;

    const float* x       = (const float*)d_in[0];
    const int*   ei      = (const int*)d_in[1];
    const float* enc_w   = (const float*)d_in[2];
    const float* enc_b   = (const float*)d_in[3];
    const float* ll_w    = (const float*)d_in[4];
    const float* ll_b    = (const float*)d_in[5];
    const float* lr_w    = (const float*)d_in[6];
    const float* bn_g    = (const float*)d_in[7];
    const float* bn_b    = (const float*)d_in[8];
    const float* bn_m    = (const float*)d_in[9];
    const float* bn_v    = (const float*)d_in[10];
    const float* out_w1  = (const float*)d_in[11];
    const float* out_b1  = (const float*)d_in[12];
    const float* out_w2  = (const float*)d_in[13];
    const float* out_b2  = (const float*)d_in[14];
    const float* cost_w1 = (const float*)d_in[15];
    const float* cost_b1 = (const float*)d_in[16];
    const float* cost_w2 = (const float*)d_in[17];
    const float* cost_b2 = (const float*)d_in[18];
    const float* bw_w1   = (const float*)d_in[19];
    const float* bw_b1   = (const float*)d_in[20];
    const float* bw_w2   = (const float*)d_in[21];
    const float* bw_b2   = (const float*)d_in[22];

    const int* e_src = ei;
    const int* e_dst = ei + NE;

    float* o_order = (float*)d_out;
    float* o_cost  = o_order + NN;
    float* o_bw    = o_cost + NN;
    float* o_h     = o_bw + NN;   // NN*128 f32 (final h)

    // workspace layout
    u16* hA = (u16*)d_ws;                       // NN*128 bf16
    u16* hB = hA + (size_t)NN * 128;            // NN*128 bf16
    u16* wt = hB + (size_t)NN * 128;            // 147456 bf16 (fragment layout)
    u16* wt_enc  = wt;
    u16* wt_ll   = wt + 16384;
    u16* wt_lr   = wt + 16384 * 4;
    u16* wt_out1 = wt + 16384 * 7;
    u16* wt_c1   = wt + 16384 * 8;
    u16* wt_bw1  = wt + 16384 * 8 + 8192;
    int* row_ptr  = (int*)(wt + 147456);        // NN+1 (+pad)
    float* inv_deg = (float*)(row_ptr + NN + 4);
    int* csr_src  = (int*)(inv_deg + NN);       // NE
    int* bcnt     = csr_src + NE;               // NBK+1
    int* bbase    = bcnt + NBK + 1;             // NBK+1
    u32* ebuf     = (u32*)(bbase + NBK + 1);    // NBK*BCAP

    const size_t need = (size_t)((char*)(ebuf + (size_t)NBK * BCAP) - (char*)d_ws);
    if (ws_size < need) return;

    (void)hipMemsetAsync(bcnt, 0, (NBK + 1) * sizeof(int), stream);

    TposeArgs ta;
    ta.src[0] = enc_w;          ta.dst[0] = wt_enc;          ta.rows[0] = 128;
    ta.src[1] = ll_w;           ta.dst[1] = wt_ll;           ta.rows[1] = 128;
    ta.src[2] = ll_w + 16384;   ta.dst[2] = wt_ll + 16384;   ta.rows[2] = 128;
    ta.src[3] = ll_w + 32768;   ta.dst[3] = wt_ll + 32768;   ta.rows[3] = 128;
    ta.src[4] = lr_w;           ta.dst[4] = wt_lr;           ta.rows[4] = 128;
    ta.src[5] = lr_w + 16384;   ta.dst[5] = wt_lr + 16384;   ta.rows[5] = 128;
    ta.src[6] = lr_w + 32768;   ta.dst[6] = wt_lr + 32768;   ta.rows[6] = 128;
    ta.src[7] = out_w1;         ta.dst[7] = wt_out1;         ta.rows[7] = 128;
    ta.src[8] = cost_w1;        ta.dst[8] = wt_c1;           ta.rows[8] = 64;
    ta.src[9] = bw_w1;          ta.dst[9] = wt_bw1;          ta.rows[9] = 64;
    frag_kernel<<<10, 256, 0, stream>>>(ta);

    bucket_scatter_kernel<<<(NE + CTILE - 1) / CTILE, 256, 0, stream>>>(e_src, e_dst, bcnt, ebuf);
    bscan_kernel<<<1, 64, 0, stream>>>(bcnt, bbase);
    csr_finalize_kernel<<<NBK, 256, 0, stream>>>(ebuf, bcnt, bbase, row_ptr, inv_deg, csr_src);

    encoder_kernel<<<NN / TN, 256, 0, stream>>>(x, hA, wt_enc, enc_b);
    sage_layer_kernel<0><<<NN / TNL, 256, 0, stream>>>(hA, hB, nullptr, wt_ll, ll_b, wt_lr,
        bn_g, bn_b, bn_m, bn_v, row_ptr, csr_src, inv_deg,
        nullptr, nullptr, nullptr, nullptr, nullptr, nullptr, nullptr, nullptr,
        nullptr, nullptr, nullptr, nullptr, nullptr, nullptr, nullptr);
    sage_layer_kernel<0><<<NN / TNL, 256, 0, stream>>>(hB, hA, nullptr, wt_ll + 16384, ll_b + 128, wt_lr + 16384,
        bn_g + 128, bn_b + 128, bn_m + 128, bn_v + 128, row_ptr, csr_src, inv_deg,
        nullptr, nullptr, nullptr, nullptr, nullptr, nullptr, nullptr, nullptr,
        nullptr, nullptr, nullptr, nullptr, nullptr, nullptr, nullptr);
    sage_layer_kernel<1><<<NN / TNL, 256, 0, stream>>>(hA, nullptr, o_h, wt_ll + 32768, ll_b + 256, wt_lr + 32768,
        bn_g + 256, bn_b + 256, bn_m + 256, bn_v + 256, row_ptr, csr_src, inv_deg,
        wt_out1, out_b1, out_w2, out_b2,
        wt_c1, cost_b1, cost_w2, cost_b2,
        wt_bw1, bw_b1, bw_w2, bw_b2,
        o_order, o_cost, o_bw);
}